// Round 2
// baseline (1071.982 us; speedup 1.0000x reference)
//
#include <hip/hip_runtime.h>
#include <stdint.h>

// Match numpy's unfused mul/add rounding everywhere (no FMA contraction).
#pragma clang fp contract(off)

// Problem constants (B=16, H=W=64, A=9, stride 16, img 1024x1024)
#define NB 16
#define NH 64
#define NW 64
#define NA 9
#define HW (NH*NW)            // 4096
#define NANCH (HW*NA)         // 36864
#define TOPN 2000
#define TOPN_PAD 2048
#define OUTN 300
#define NWORDS 32             // ceil(2000/64)

// 9 base anchors (x1,y1,x2,y2), computed exactly per the numpy generator
__constant__ float c_ax1[9] = {-3.5f,-15.f,-38.f,  0.f, -8.f,-24.f,  2.5f, -3.f,-14.f};
__constant__ float c_ay1[9] = { 2.f,  -4.f,-16.f,  0.f, -8.f,-24.f, -3.f,-14.f,-36.f};
__constant__ float c_ax2[9] = {18.5f, 30.f, 53.f, 15.f, 23.f, 39.f, 12.5f, 18.f, 29.f};
__constant__ float c_ay2[9] = {13.f,  19.f, 31.f, 15.f, 23.f, 39.f, 18.f,  29.f, 51.f};

__device__ __forceinline__ void decode_box(int a, int x, int y,
    float d0, float d1, float d2, float d3,
    float& x1, float& y1, float& x2, float& y2) {
  float ax1 = c_ax1[a] + 16.f * (float)x;
  float ay1 = c_ay1[a] + 16.f * (float)y;
  float ax2 = c_ax2[a] + 16.f * (float)x;
  float ay2 = c_ay2[a] + 16.f * (float)y;
  float aw  = ax2 - ax1 + 1.f;
  float ah  = ay2 - ay1 + 1.f;
  float acx = ax1 + 0.5f * aw;
  float acy = ay1 + 0.5f * ah;
  float cx = d0 * aw + acx;
  float cy = d1 * ah + acy;
  float pw = expf(d2) * aw;
  float ph = expf(d3) * ah;
  x1 = cx - 0.5f * pw;
  y1 = cy - 0.5f * ph;
  x2 = cx + 0.5f * pw;
  y2 = cy + 0.5f * ph;
  x1 = fminf(fmaxf(x1, 0.f), 1023.f);
  y1 = fminf(fmaxf(y1, 0.f), 1023.f);
  x2 = fminf(fmaxf(x2, 0.f), 1023.f);
  y2 = fminf(fmaxf(y2, 0.f), 1023.f);
}

// monotone float -> u32 (descending float == descending u32)
__device__ __forceinline__ uint32_t f2ord(float f) {
  uint32_t u = __float_as_uint(f);
  return (u & 0x80000000u) ? ~u : (u | 0x80000000u);
}
__device__ __forceinline__ float ord2f(uint32_t u) {
  return (u & 0x80000000u) ? __uint_as_float(u ^ 0x80000000u) : __uint_as_float(~u);
}

// Kernel 1: masked ordered score keys for every anchor.
// thread t <-> (b, a, pos) with pos fastest (coalesced channel-major loads)
__global__ void k_score(const float* __restrict__ labels, const float* __restrict__ bbox,
                        uint32_t* __restrict__ keys) {
  int t = blockIdx.x * 256 + threadIdx.x;
  if (t >= NB * NA * HW) return;
  int pos = t & (HW - 1);
  int ba  = t >> 12;          // b*9 + a
  int a = ba % 9;
  int b = ba / 9;
  float score = labels[((b * 18 + 2 * a + 1) << 12) + pos];
  const float* dp = bbox + ((b * 36 + 4 * a) << 12) + pos;
  float d0 = dp[0], d1 = dp[4096], d2 = dp[8192], d3 = dp[12288];
  int y = pos >> 6, x = pos & 63;
  float x1, y1, x2, y2;
  decode_box(a, x, y, d0, d1, d2, d3, x1, y1, x2, y2);
  bool keep = (x2 - x1 + 1.f >= 16.f) && (y2 - y1 + 1.f >= 16.f);
  float s = keep ? score : -INFINITY;
  keys[b * NANCH + pos * 9 + a] = f2ord(s);
}

// Kernel 2: per-batch radix select (top-2000 threshold + tie count), then stable
// compaction of the exact top-2000 set into composite 64-bit sort keys.
__global__ void k_select(const uint32_t* __restrict__ keys,
                         unsigned long long* __restrict__ selKeys) {
  int b = blockIdx.x;
  int tid = threadIdx.x;             // 256 threads
  const uint32_t* kb = keys + b * NANCH;
  __shared__ unsigned int hist[256];
  __shared__ unsigned int sh_prefix;
  __shared__ int sh_remaining;
  __shared__ unsigned int sh_cntgt;
  __shared__ int sh_runeq;
  __shared__ unsigned int wv[4];

  unsigned int prefix = 0;
  int remaining = TOPN;
  for (int round = 0; round < 4; ++round) {
    int shift = 24 - 8 * round;
    hist[tid] = 0u;
    __syncthreads();
    for (int i = tid; i < NANCH; i += 256) {
      uint32_t u = kb[i];
      bool m = (round == 0) || ((u >> (shift + 8)) == prefix);
      if (m) atomicAdd(&hist[(u >> shift) & 255u], 1u);
    }
    __syncthreads();
    if (tid == 0) {
      unsigned int acc = 0;
      for (int bkt = 255;; --bkt) {
        unsigned int c = hist[bkt];
        if (acc + c >= (unsigned int)remaining) {
          sh_prefix = (prefix << 8) | (unsigned int)bkt;
          sh_remaining = remaining - (int)acc;
          break;
        }
        acc += c;
      }
    }
    __syncthreads();
    prefix = sh_prefix;
    remaining = sh_remaining;
    __syncthreads();
  }
  uint32_t T = prefix;
  int R = remaining;              // take first R (by index) of keys == T
  if (tid == 0) { sh_cntgt = 0u; sh_runeq = 0; }
  __syncthreads();
  int wave = tid >> 6, lane = tid & 63;
  for (int base = 0; base < NANCH; base += 256) {   // 36864 % 256 == 0
    int i = base + tid;
    uint32_t u = kb[i];
    bool gt = (u > T);
    bool eq = (u == T);
    if (gt) {
      unsigned int slot = atomicAdd(&sh_cntgt, 1u);  // set is deterministic; order fixed by sort
      selKeys[b * TOPN_PAD + slot] = (((unsigned long long)(~u)) << 32) | (unsigned int)i;
    }
    unsigned long long mb = __ballot(eq);
    if (lane == 0) wv[wave] = (unsigned int)__popcll(mb);
    __syncthreads();
    int woff = 0;
    for (int w2 = 0; w2 < wave; ++w2) woff += (int)wv[w2];
    int rank = sh_runeq + woff + __popcll(mb & ((1ull << lane) - 1ull));
    if (eq && rank < R) {
      selKeys[b * TOPN_PAD + (TOPN - R) + rank] = (((unsigned long long)(~u)) << 32) | (unsigned int)i;
    }
    __syncthreads();
    if (tid == 0) sh_runeq += (int)(wv[0] + wv[1] + wv[2] + wv[3]);
    __syncthreads();
  }
  if (tid < TOPN_PAD - TOPN) selKeys[b * TOPN_PAD + TOPN + tid] = ~0ull;
}

// Kernel 3: per-batch bitonic sort of 2048 composite keys -> (score desc, idx asc)
__global__ void k_sort(const unsigned long long* __restrict__ selKeys,
                       uint32_t* __restrict__ selIdx, float* __restrict__ selScore) {
  int b = blockIdx.x;
  int tid = threadIdx.x;           // 1024 threads
  __shared__ unsigned long long s[TOPN_PAD];
  s[tid] = selKeys[b * TOPN_PAD + tid];
  s[tid + 1024] = selKeys[b * TOPN_PAD + tid + 1024];
  __syncthreads();
  for (int k = 2; k <= TOPN_PAD; k <<= 1) {
    for (int j = k >> 1; j > 0; j >>= 1) {
      for (int e = tid; e < TOPN_PAD; e += 1024) {
        int ixj = e ^ j;
        if (ixj > e) {
          bool up = ((e & k) == 0);
          unsigned long long A2 = s[e], B2 = s[ixj];
          if ((A2 > B2) == up) { s[e] = B2; s[ixj] = A2; }
        }
      }
      __syncthreads();
    }
  }
  for (int r = tid; r < TOPN; r += 1024) {
    unsigned long long kk = s[r];
    selIdx[b * TOPN + r] = (uint32_t)kk;
    selScore[b * TOPN + r] = ord2f(~((uint32_t)(kk >> 32)));
  }
}

// Kernel 4: decode+clip the selected 2000 boxes per batch
__global__ void k_decode(const float* __restrict__ bbox, const uint32_t* __restrict__ selIdx,
                         float4* __restrict__ boxes) {
  int q = blockIdx.x * 256 + threadIdx.x;
  if (q >= NB * TOPN) return;
  int b = q / TOPN, r = q % TOPN;
  int idx = (int)selIdx[b * TOPN + r];
  int pos = idx / 9, a = idx % 9;
  int y = pos >> 6, x = pos & 63;
  const float* dp = bbox + ((b * 36 + 4 * a) << 12) + pos;
  float d0 = dp[0], d1 = dp[4096], d2 = dp[8192], d3 = dp[12288];
  float x1, y1, x2, y2;
  decode_box(a, x, y, d0, d1, d2, d3, x1, y1, x2, y2);
  boxes[b * TOPN + r] = make_float4(x1, y1, x2, y2);
}

// Kernel 5: 64x64 suppression bitmask tiles (bit j set iff j>i && iou(i,j)>0.7)
__global__ void k_iou(const float4* __restrict__ boxes, unsigned long long* __restrict__ masks) {
  int cb = blockIdx.x, rb = blockIdx.y, b = blockIdx.z;
  int tid = threadIdx.x;           // 64 threads
  __shared__ float4 colB[64];
  int j = cb * 64 + tid;
  colB[tid] = (j < TOPN) ? boxes[b * TOPN + j] : make_float4(0.f, 0.f, 0.f, 0.f);
  __syncthreads();
  int i = rb * 64 + tid;
  if (i >= TOPN) return;
  float4 bi = boxes[b * TOPN + i];
  float areai = (bi.z - bi.x + 1.f) * (bi.w - bi.y + 1.f);
  unsigned long long m = 0ull;
  for (int jj = 0; jj < 64; ++jj) {
    int j2 = cb * 64 + jj;
    if (j2 > i && j2 < TOPN) {
      float4 bj = colB[jj];
      float iw = fminf(bi.z, bj.z) - fmaxf(bi.x, bj.x) + 1.f;
      iw = fmaxf(0.f, iw);
      float ih = fminf(bi.w, bj.w) - fmaxf(bi.y, bj.y) + 1.f;
      ih = fmaxf(0.f, ih);
      float inter = iw * ih;
      float areaj = (bj.z - bj.x + 1.f) * (bj.w - bj.y + 1.f);
      float iou = inter / (areai + areaj - inter);
      if (iou > 0.7f) m |= (1ull << jj);
    }
  }
  masks[((size_t)(b * TOPN + i)) * NWORDS + cb] = m;
}

// Kernel 6: per-batch greedy scan (one wave) + write output
// out layout: boxes f32[16][300][4] at offset 0, scores f32[16][300] at 19200
__global__ void k_greedy(const unsigned long long* __restrict__ masks,
                         const float4* __restrict__ boxes, const float* __restrict__ scores,
                         float* __restrict__ out) {
  int b = blockIdx.x, tid = threadIdx.x;   // 64 threads = 1 wave
  __shared__ unsigned long long sup[NWORDS];
  __shared__ int kept[OUTN];
  __shared__ int cnt;
  if (tid < NWORDS) sup[tid] = 0ull;
  if (tid == 0) cnt = 0;
  __syncthreads();
  for (int i = 0; i < TOPN; ++i) {
    bool suppressed = (sup[i >> 6] >> (i & 63)) & 1ull;   // uniform
    if (!suppressed) {
      if (tid < NWORDS) sup[tid] |= masks[((size_t)(b * TOPN + i)) * NWORDS + tid];
      if (tid == 0) { if (cnt < OUTN) kept[cnt] = i; cnt++; }
    }
    __syncthreads();
  }
  int c = cnt;
  float4* ob = (float4*)out;
  for (int s2 = tid; s2 < OUTN; s2 += 64) {
    float4 bx = make_float4(0.f, 0.f, 0.f, 0.f);
    float sc = 0.f;
    if (s2 < c) {
      int i = kept[s2];
      bx = boxes[b * TOPN + i];
      sc = scores[b * TOPN + i];
    }
    ob[b * OUTN + s2] = bx;
    out[NB * OUTN * 4 + b * OUTN + s2] = sc;
  }
}

extern "C" void kernel_launch(void* const* d_in, const int* in_sizes, int n_in,
                              void* d_out, int out_size, void* d_ws, size_t ws_size,
                              hipStream_t stream) {
  const float* labels = (const float*)d_in[0];  // (16, 18, 64, 64)
  const float* bbox   = (const float*)d_in[1];  // (16, 36, 64, 64)
  char* ws = (char*)d_ws;
  // workspace layout (bytes):
  uint32_t* keys               = (uint32_t*)(ws + 0);                 // 16*36864*4   = 2,359,296
  unsigned long long* selKeys  = (unsigned long long*)(ws + 2359296); // 16*2048*8    =   262,144
  uint32_t* selIdx             = (uint32_t*)(ws + 2621440);           // 16*2048*4    =   131,072
  float* selScore              = (float*)(ws + 2752512);              // 16*2048*4    =   131,072
  float4* boxes                = (float4*)(ws + 2883584);             // 16*2048*16   =   524,288
  unsigned long long* masks    = (unsigned long long*)(ws + 3407872); // 16*2000*32*8 = 8,192,000
  float* out = (float*)d_out;

  hipLaunchKernelGGL(k_score,  dim3((NB*NA*HW + 255) / 256), dim3(256), 0, stream, labels, bbox, keys);
  hipLaunchKernelGGL(k_select, dim3(NB),  dim3(256),  0, stream, keys, selKeys);
  hipLaunchKernelGGL(k_sort,   dim3(NB),  dim3(1024), 0, stream, selKeys, selIdx, selScore);
  hipLaunchKernelGGL(k_decode, dim3((NB*TOPN + 255) / 256), dim3(256), 0, stream, bbox, selIdx, boxes);
  hipLaunchKernelGGL(k_iou,    dim3(32, 32, NB), dim3(64), 0, stream, boxes, masks);
  hipLaunchKernelGGL(k_greedy, dim3(NB), dim3(64), 0, stream, masks, boxes, selScore, out);
}

// Round 3
// 229.768 us; speedup vs baseline: 4.6655x; 4.6655x over previous
//
#include <hip/hip_runtime.h>
#include <stdint.h>

// Match numpy's unfused mul/add rounding everywhere (no FMA contraction).
#pragma clang fp contract(off)

// Problem constants (B=16, H=W=64, A=9, stride 16, img 1024x1024)
#define NB 16
#define NH 64
#define NW 64
#define NA 9
#define HW (NH*NW)            // 4096
#define NANCH (HW*NA)         // 36864
#define TOPN 2000
#define TOPN_PAD 2048
#define OUTN 300
#define NWORDS 32             // ceil(2000/64) ull words per mask row
#define GD 16                 // greedy prefetch pipeline depth

// 9 base anchors (x1,y1,x2,y2), computed exactly per the numpy generator
__constant__ float c_ax1[9] = {-3.5f,-15.f,-38.f,  0.f, -8.f,-24.f,  2.5f, -3.f,-14.f};
__constant__ float c_ay1[9] = { 2.f,  -4.f,-16.f,  0.f, -8.f,-24.f, -3.f,-14.f,-36.f};
__constant__ float c_ax2[9] = {18.5f, 30.f, 53.f, 15.f, 23.f, 39.f, 12.5f, 18.f, 29.f};
__constant__ float c_ay2[9] = {13.f,  19.f, 31.f, 15.f, 23.f, 39.f, 18.f,  29.f, 51.f};

__device__ __forceinline__ void decode_box(int a, int x, int y,
    float d0, float d1, float d2, float d3,
    float& x1, float& y1, float& x2, float& y2) {
  float ax1 = c_ax1[a] + 16.f * (float)x;
  float ay1 = c_ay1[a] + 16.f * (float)y;
  float ax2 = c_ax2[a] + 16.f * (float)x;
  float ay2 = c_ay2[a] + 16.f * (float)y;
  float aw  = ax2 - ax1 + 1.f;
  float ah  = ay2 - ay1 + 1.f;
  float acx = ax1 + 0.5f * aw;
  float acy = ay1 + 0.5f * ah;
  float cx = d0 * aw + acx;
  float cy = d1 * ah + acy;
  float pw = expf(d2) * aw;
  float ph = expf(d3) * ah;
  x1 = cx - 0.5f * pw;
  y1 = cy - 0.5f * ph;
  x2 = cx + 0.5f * pw;
  y2 = cy + 0.5f * ph;
  x1 = fminf(fmaxf(x1, 0.f), 1023.f);
  y1 = fminf(fmaxf(y1, 0.f), 1023.f);
  x2 = fminf(fmaxf(x2, 0.f), 1023.f);
  y2 = fminf(fmaxf(y2, 0.f), 1023.f);
}

// monotone float -> u32 (descending float == descending u32)
__device__ __forceinline__ uint32_t f2ord(float f) {
  uint32_t u = __float_as_uint(f);
  return (u & 0x80000000u) ? ~u : (u | 0x80000000u);
}
__device__ __forceinline__ float ord2f(uint32_t u) {
  return (u & 0x80000000u) ? __uint_as_float(u ^ 0x80000000u) : __uint_as_float(~u);
}

// Kernel 1: masked ordered score keys for every anchor.
__global__ void k_score(const float* __restrict__ labels, const float* __restrict__ bbox,
                        uint32_t* __restrict__ keys) {
  int t = blockIdx.x * 256 + threadIdx.x;
  if (t >= NB * NA * HW) return;
  int pos = t & (HW - 1);
  int ba  = t >> 12;          // b*9 + a
  int a = ba % 9;
  int b = ba / 9;
  float score = labels[((b * 18 + 2 * a + 1) << 12) + pos];
  const float* dp = bbox + ((b * 36 + 4 * a) << 12) + pos;
  float d0 = dp[0], d1 = dp[4096], d2 = dp[8192], d3 = dp[12288];
  int y = pos >> 6, x = pos & 63;
  float x1, y1, x2, y2;
  decode_box(a, x, y, d0, d1, d2, d3, x1, y1, x2, y2);
  bool keep = (x2 - x1 + 1.f >= 16.f) && (y2 - y1 + 1.f >= 16.f);
  float s = keep ? score : -INFINITY;
  keys[b * NANCH + pos * 9 + a] = f2ord(s);
}

// Kernel 2: per-batch radix select (top-2000 threshold + tie count), then stable
// compaction of the exact top-2000 set into composite 64-bit sort keys.
// 1024 threads = 16 waves.
__global__ void k_select(const uint32_t* __restrict__ keys,
                         unsigned long long* __restrict__ selKeys) {
  int b = blockIdx.x;
  int tid = threadIdx.x;             // 1024 threads
  const uint32_t* kb = keys + b * NANCH;
  __shared__ unsigned int hist[256];
  __shared__ unsigned int sh_prefix;
  __shared__ int sh_remaining;
  __shared__ unsigned int sh_cntgt;
  __shared__ int sh_runeq;
  __shared__ unsigned int wv[16];

  unsigned int prefix = 0;
  int remaining = TOPN;
  for (int round = 0; round < 4; ++round) {
    int shift = 24 - 8 * round;
    if (tid < 256) hist[tid] = 0u;
    __syncthreads();
    for (int i = tid; i < NANCH; i += 1024) {
      uint32_t u = kb[i];
      bool m = (round == 0) || ((u >> (shift + 8)) == prefix);
      if (m) atomicAdd(&hist[(u >> shift) & 255u], 1u);
    }
    __syncthreads();
    if (tid == 0) {
      unsigned int acc = 0;
      for (int bkt = 255;; --bkt) {
        unsigned int c = hist[bkt];
        if (acc + c >= (unsigned int)remaining) {
          sh_prefix = (prefix << 8) | (unsigned int)bkt;
          sh_remaining = remaining - (int)acc;
          break;
        }
        acc += c;
      }
    }
    __syncthreads();
    prefix = sh_prefix;
    remaining = sh_remaining;
    __syncthreads();
  }
  uint32_t T = prefix;
  int R = remaining;              // take first R (by index) of keys == T
  if (tid == 0) { sh_cntgt = 0u; sh_runeq = 0; }
  __syncthreads();
  int wave = tid >> 6, lane = tid & 63;
  for (int base = 0; base < NANCH; base += 1024) {   // 36864 % 1024 == 0
    int i = base + tid;
    uint32_t u = kb[i];
    bool gt = (u > T);
    bool eq = (u == T);
    if (gt) {
      unsigned int slot = atomicAdd(&sh_cntgt, 1u);  // set deterministic; order fixed by sort
      selKeys[b * TOPN_PAD + slot] = (((unsigned long long)(~u)) << 32) | (unsigned int)i;
    }
    unsigned long long mb = __ballot(eq);
    if (lane == 0) wv[wave] = (unsigned int)__popcll(mb);
    __syncthreads();
    int woff = 0;
    for (int w2 = 0; w2 < wave; ++w2) woff += (int)wv[w2];
    int rank = sh_runeq + woff + __popcll(mb & ((1ull << lane) - 1ull));
    if (eq && rank < R) {
      selKeys[b * TOPN_PAD + (TOPN - R) + rank] = (((unsigned long long)(~u)) << 32) | (unsigned int)i;
    }
    __syncthreads();
    if (tid == 0) {
      int s = 0;
      for (int w2 = 0; w2 < 16; ++w2) s += (int)wv[w2];
      sh_runeq += s;
    }
    __syncthreads();
  }
  if (tid < TOPN_PAD - TOPN) selKeys[b * TOPN_PAD + TOPN + tid] = ~0ull;
}

// Kernel 3: per-batch bitonic sort of 2048 composite keys -> (score desc, idx asc)
__global__ void k_sort(const unsigned long long* __restrict__ selKeys,
                       uint32_t* __restrict__ selIdx, float* __restrict__ selScore) {
  int b = blockIdx.x;
  int tid = threadIdx.x;           // 1024 threads
  __shared__ unsigned long long s[TOPN_PAD];
  s[tid] = selKeys[b * TOPN_PAD + tid];
  s[tid + 1024] = selKeys[b * TOPN_PAD + tid + 1024];
  __syncthreads();
  for (int k = 2; k <= TOPN_PAD; k <<= 1) {
    for (int j = k >> 1; j > 0; j >>= 1) {
      for (int e = tid; e < TOPN_PAD; e += 1024) {
        int ixj = e ^ j;
        if (ixj > e) {
          bool up = ((e & k) == 0);
          unsigned long long A2 = s[e], B2 = s[ixj];
          if ((A2 > B2) == up) { s[e] = B2; s[ixj] = A2; }
        }
      }
      __syncthreads();
    }
  }
  for (int r = tid; r < TOPN; r += 1024) {
    unsigned long long kk = s[r];
    selIdx[b * TOPN + r] = (uint32_t)kk;
    selScore[b * TOPN + r] = ord2f(~((uint32_t)(kk >> 32)));
  }
}

// Kernel 4: decode+clip the selected 2000 boxes per batch
__global__ void k_decode(const float* __restrict__ bbox, const uint32_t* __restrict__ selIdx,
                         float4* __restrict__ boxes) {
  int q = blockIdx.x * 256 + threadIdx.x;
  if (q >= NB * TOPN) return;
  int b = q / TOPN, r = q % TOPN;
  int idx = (int)selIdx[b * TOPN + r];
  int pos = idx / 9, a = idx % 9;
  int y = pos >> 6, x = pos & 63;
  const float* dp = bbox + ((b * 36 + 4 * a) << 12) + pos;
  float d0 = dp[0], d1 = dp[4096], d2 = dp[8192], d3 = dp[12288];
  float x1, y1, x2, y2;
  decode_box(a, x, y, d0, d1, d2, d3, x1, y1, x2, y2);
  boxes[b * TOPN + r] = make_float4(x1, y1, x2, y2);
}

// Kernel 5: 64x64 suppression bitmask tiles (bit j set iff j>i && iou(i,j)>0.7)
__global__ void k_iou(const float4* __restrict__ boxes, unsigned long long* __restrict__ masks) {
  int cb = blockIdx.x, rb = blockIdx.y, b = blockIdx.z;
  int tid = threadIdx.x;           // 64 threads
  __shared__ float4 colB[64];
  int j = cb * 64 + tid;
  colB[tid] = (j < TOPN) ? boxes[b * TOPN + j] : make_float4(0.f, 0.f, 0.f, 0.f);
  __syncthreads();
  int i = rb * 64 + tid;
  if (i >= TOPN) return;
  float4 bi = boxes[b * TOPN + i];
  float areai = (bi.z - bi.x + 1.f) * (bi.w - bi.y + 1.f);
  unsigned long long m = 0ull;
  for (int jj = 0; jj < 64; ++jj) {
    int j2 = cb * 64 + jj;
    if (j2 > i && j2 < TOPN) {
      float4 bj = colB[jj];
      float iw = fminf(bi.z, bj.z) - fmaxf(bi.x, bj.x) + 1.f;
      iw = fmaxf(0.f, iw);
      float ih = fminf(bi.w, bj.w) - fmaxf(bi.y, bj.y) + 1.f;
      ih = fmaxf(0.f, ih);
      float inter = iw * ih;
      float areaj = (bj.z - bj.x + 1.f) * (bj.w - bj.y + 1.f);
      float iou = inter / (areai + areaj - inter);
      if (iou > 0.7f) m |= (1ull << jj);
    }
  }
  masks[((size_t)(b * TOPN + i)) * NWORDS + cb] = m;
}

// Kernel 6: per-batch greedy scan, single wave, suppression bitmap in registers
// (lane l owns u32 word l of the 2000-bit map), 16-deep register prefetch of
// mask rows, early exit once 300 boxes are kept (provably exact: output only
// depends on the first min(kept,300) kept boxes).
// out layout: boxes f32[16][300][4] at offset 0, scores f32[16][300] at 19200
__global__ void k_greedy(const unsigned long long* __restrict__ masks,
                         const float4* __restrict__ boxes, const float* __restrict__ scores,
                         float* __restrict__ out) {
  int b = blockIdx.x, lane = threadIdx.x;   // 64 threads = 1 wave
  const uint32_t* mrows = (const uint32_t*)(masks + (size_t)(b * TOPN) * NWORDS);
  // row i occupies mrows[i*64 .. i*64+63]; lane's word = mrows[i*64 + lane]
  uint32_t m[GD];
#pragma unroll
  for (int ph = 0; ph < GD; ++ph) m[ph] = mrows[ph * 64 + lane];

  uint32_t supw = 0u;                 // suppression word owned by this lane
  __shared__ int kept[OUTN];
  int cnt = 0;                        // wave-uniform by construction

  for (int base = 0; base < TOPN; base += GD) {
#pragma unroll
    for (int ph = 0; ph < GD; ++ph) {
      int i = base + ph;
      uint32_t sw = __shfl(supw, i >> 5);          // broadcast word holding bit i
      if (!((sw >> (i & 31)) & 1u)) {              // uniform condition
        supw |= m[ph];
        if (lane == 0 && cnt < OUTN) kept[cnt] = i;
        cnt++;
      }
      int nx = i + GD; if (nx > TOPN - 1) nx = TOPN - 1;
      m[ph] = mrows[nx * 64 + lane];               // prefetch GD rows ahead
    }
    if (cnt >= OUTN) break;                        // exact early exit
  }
  __syncthreads();                                 // kept[] visible to all lanes

  int c = cnt < OUTN ? cnt : OUTN;
  float4* ob = (float4*)out;
  for (int s2 = lane; s2 < OUTN; s2 += 64) {
    float4 bx = make_float4(0.f, 0.f, 0.f, 0.f);
    float sc = 0.f;
    if (s2 < c) {
      int i = kept[s2];
      bx = boxes[b * TOPN + i];
      sc = scores[b * TOPN + i];
    }
    ob[b * OUTN + s2] = bx;
    out[NB * OUTN * 4 + b * OUTN + s2] = sc;
  }
}

extern "C" void kernel_launch(void* const* d_in, const int* in_sizes, int n_in,
                              void* d_out, int out_size, void* d_ws, size_t ws_size,
                              hipStream_t stream) {
  const float* labels = (const float*)d_in[0];  // (16, 18, 64, 64)
  const float* bbox   = (const float*)d_in[1];  // (16, 36, 64, 64)
  char* ws = (char*)d_ws;
  // workspace layout (bytes):
  uint32_t* keys               = (uint32_t*)(ws + 0);                 // 16*36864*4   = 2,359,296
  unsigned long long* selKeys  = (unsigned long long*)(ws + 2359296); // 16*2048*8    =   262,144
  uint32_t* selIdx             = (uint32_t*)(ws + 2621440);           // 16*2048*4    =   131,072
  float* selScore              = (float*)(ws + 2752512);              // 16*2048*4    =   131,072
  float4* boxes                = (float4*)(ws + 2883584);             // 16*2048*16   =   524,288
  unsigned long long* masks    = (unsigned long long*)(ws + 3407872); // 16*2000*32*8 = 8,192,000
  float* out = (float*)d_out;

  hipLaunchKernelGGL(k_score,  dim3((NB*NA*HW + 255) / 256), dim3(256), 0, stream, labels, bbox, keys);
  hipLaunchKernelGGL(k_select, dim3(NB),  dim3(1024), 0, stream, keys, selKeys);
  hipLaunchKernelGGL(k_sort,   dim3(NB),  dim3(1024), 0, stream, selKeys, selIdx, selScore);
  hipLaunchKernelGGL(k_decode, dim3((NB*TOPN + 255) / 256), dim3(256), 0, stream, bbox, selIdx, boxes);
  hipLaunchKernelGGL(k_iou,    dim3(32, 32, NB), dim3(64), 0, stream, boxes, masks);
  hipLaunchKernelGGL(k_greedy, dim3(NB), dim3(64), 0, stream, masks, boxes, selScore, out);
}